// Round 4
// baseline (202.429 us; speedup 1.0000x reference)
//
#include <hip/hip_runtime.h>
#include <hip/hip_bf16.h>

// QLSTM: T=512, B=256, D_IN=128, D_H=128.
// Gates are per-batch SCALARS broadcast over hidden dim => h,c uniform across
// hidden dim. comb@W[0] = x@W[0][:128] + h*sum(W[0][128:]).
// Pipeline: (1) xz GEMV -> packed float4 (pre-scaled by 1/2pi), float4 loads,
//               W cached in regs, grid-stride (mem-bound),
//           (2) 512-step scan: 16 blocks x 1 wave, 4 lanes per batch element
//               (one gate per lane), DPP quad_perm gate exchange, unified
//               odd deg-7 polynomial gates, scalar register prefetch depth 16,
//           (3) broadcast h[t,b] to 128 cols + hx/cx tails (write-bound).

constexpr int T = 512;
constexpr int Bsz = 256;
constexpr int R = T * Bsz;          // 131072 rows
constexpr float INV2PI = 0.15915494309189535f;

// ---------------- Kernel 1: xz[row] = float4(zf,zi,zu,zo)/(2pi), row = t*B+b
// 2048 blocks x 256 threads, 2 rows per wave per iter (half-wave per row),
// float4 loads, W rows cached in registers, 8 grid-stride iterations.
__global__ __launch_bounds__(256) void xz_kernel(
    const float* __restrict__ x,
    const float* __restrict__ Wf, const float* __restrict__ bf, const float* __restrict__ tf,
    const float* __restrict__ Wi, const float* __restrict__ bi, const float* __restrict__ ti,
    const float* __restrict__ Wu, const float* __restrict__ bu, const float* __restrict__ tu,
    const float* __restrict__ Wo, const float* __restrict__ bo, const float* __restrict__ to_,
    float4* __restrict__ xz)
{
    const int wglobal = blockIdx.x * 4 + (threadIdx.x >> 6);   // 0..8191
    const int lane = threadIdx.x & 63;
    const int hl = lane & 31;            // lane within half-wave
    const int half = lane >> 5;          // which row of the pair

    const float4 wfv = ((const float4*)Wf)[hl];
    const float4 wiv = ((const float4*)Wi)[hl];
    const float4 wuv = ((const float4*)Wu)[hl];
    const float4 wov = ((const float4*)Wo)[hl];

    const float cf = bf[0] + tf[0];
    const float ci = bi[0] + ti[0];
    const float cu = bu[0] + tu[0];
    const float co = bo[0] + to_[0];

    for (int it = 0; it < 8; ++it) {
        const int row = (it * 8192 + wglobal) * 2 + half;
        const float4 xv = *(const float4*)(x + (size_t)row * 128 + hl * 4);

        float pf = xv.x * wfv.x + xv.y * wfv.y + xv.z * wfv.z + xv.w * wfv.w;
        float pi = xv.x * wiv.x + xv.y * wiv.y + xv.z * wiv.z + xv.w * wiv.w;
        float pu = xv.x * wuv.x + xv.y * wuv.y + xv.z * wuv.z + xv.w * wuv.w;
        float po = xv.x * wov.x + xv.y * wov.y + xv.z * wov.z + xv.w * wov.w;

#pragma unroll
        for (int off = 16; off; off >>= 1) {
            pf += __shfl_xor(pf, off, 64);
            pi += __shfl_xor(pi, off, 64);
            pu += __shfl_xor(pu, off, 64);
            po += __shfl_xor(po, off, 64);
        }
        if (hl == 0) {
            xz[row] = make_float4((pf + cf) * INV2PI, (pi + ci) * INV2PI,
                                  (pu + cu) * INV2PI, (po + co) * INV2PI);
        }
    }
}

// ---------------- Kernel 2: sequential scan.
// tanh(c), |c|<=~2.1: Pade[5/4] c(945+105c^2+c^4)/(945+420c^2+15c^4), err ~2e-5.
__device__ __forceinline__ float tanh_p54(float c) {
    const float c2 = c * c;
    const float c4 = c2 * c2;
    const float num = fmaf(c2, 105.0f, 945.0f) + c4;
    const float den = fmaf(c4, 15.0f, fmaf(c2, 420.0f, 945.0f));
    return c * num * __builtin_amdgcn_rcpf(den);
}

template<int CTRL>
__device__ __forceinline__ float dppq(float x) {
    return __builtin_bit_cast(float,
        __builtin_amdgcn_mov_dpp(__builtin_bit_cast(int, x), CTRL, 0xF, 0xF, true));
}

constexpr int PF = 16;  // prefetch depth (T % PF == 0)

__global__ __launch_bounds__(64, 1) void scan_kernel(
    const float* __restrict__ xzf,   // R*4 floats, row t is 1024 consecutive floats
    const float* __restrict__ Wf, const float* __restrict__ Wi,
    const float* __restrict__ Wu, const float* __restrict__ Wo,
    float* __restrict__ hscan, float* __restrict__ cfin)
{
    const int l = threadIdx.x;
    const int q = l & 3;                     // gate: 0=f 1=i 2=g 3=o
    const int bg = l >> 2;                   // batch-in-block 0..15
    const int batch = blockIdx.x * 16 + bg;
    const int base = blockIdx.x * 64;        // column base within the 1024-wide row

    // per-gate hidden-weight sum: 16 lanes of the same q cooperate
    const float* Wsel = (q == 0) ? Wf : (q == 1) ? Wi : (q == 2) ? Wu : Wo;
    const float4 wa = *(const float4*)(Wsel + 128 + bg * 8);
    const float4 wb = *(const float4*)(Wsel + 128 + bg * 8 + 4);
    float s = wa.x + wa.y + wa.z + wa.w + wb.x + wb.y + wb.z + wb.w;
    s += __shfl_xor(s, 4, 64);
    s += __shfl_xor(s, 8, 64);
    s += __shfl_xor(s, 16, 64);
    s += __shfl_xor(s, 32, 64);
    const float sw = s * INV2PI;

    // unified odd deg-7 gate polynomial in v = cos(u):
    //   tanh lane (q==2):   tanh(v)
    //   sigmoid lanes:      0.5 + 0.5*tanh(v/2)   (exact identity, folded coeffs)
    const bool tq = (q == 2);
    const float K0 = tq ? 0.0f        : 0.5f;
    const float K1 = tq ? 0.999904f   : 0.249976f;
    const float K3 = tq ? -0.331066f  : -0.0206916f;
    const float K5 = tq ? 0.120476f   : 0.00188244f;
    const float K7 = tq ? -0.0277200f : -0.000108281f;

    float h = 0.0f, c = 0.0f;

    float buf[PF];
#pragma unroll
    for (int d = 0; d < PF; ++d) buf[d] = xzf[d * 1024 + base + l];

    for (int tb = 0; tb < T; tb += PF) {
        const bool more = (tb + PF) < T;
#pragma unroll
        for (int d = 0; d < PF; ++d) {
            const int t = tb + d;
            const float z = buf[d];
            if (more) buf[d] = xzf[(t + PF) * 1024 + base + l];

            const float u = fmaf(h, sw, z);          // revolutions
            const float v = __builtin_amdgcn_cosf(u);
            const float v2 = v * v;
            float p = fmaf(v2, K7, K5);
            p = fmaf(v2, p, K3);
            p = fmaf(v2, p, K1);
            const float gown = fmaf(v, p, K0);       // this lane's gate value

            const float f = dppq<0x00>(gown);
            const float i = dppq<0x55>(gown);
            const float g = dppq<0xAA>(gown);
            const float o = dppq<0xFF>(gown);

            c = fmaf(f, c, i * g);
            h = o * tanh_p54(c);
            if (q == 0) hscan[t * Bsz + batch] = h;
        }
    }
    if (q == 0) cfin[batch] = c;
}

// ---------------- Kernel 3: broadcast h[t,b] across 128 hidden cols, + hx/cx tails.
__global__ __launch_bounds__(256) void bcast_kernel(
    const float* __restrict__ hscan, const float* __restrict__ cfin,
    float4* __restrict__ out)
{
    const unsigned i = blockIdx.x * 256u + threadIdx.x;  // float4 index
    const unsigned row = i >> 5;                          // output row (128 floats)
    float v;
    if (row < (unsigned)R) {
        v = hscan[row];
    } else {
        const unsigned r2 = row - (unsigned)R;
        v = (r2 < (unsigned)Bsz) ? hscan[(T - 1) * Bsz + r2] : cfin[r2 - (unsigned)Bsz];
    }
    out[i] = make_float4(v, v, v, v);
}

extern "C" void kernel_launch(void* const* d_in, const int* in_sizes, int n_in,
                              void* d_out, int out_size, void* d_ws, size_t ws_size,
                              hipStream_t stream)
{
    const float* x  = (const float*)d_in[0];
    const float* Wf = (const float*)d_in[1];
    const float* bf = (const float*)d_in[2];
    const float* tf = (const float*)d_in[3];
    const float* Wi = (const float*)d_in[4];
    const float* bi = (const float*)d_in[5];
    const float* ti = (const float*)d_in[6];
    const float* Wu = (const float*)d_in[7];
    const float* bu = (const float*)d_in[8];
    const float* tu = (const float*)d_in[9];
    const float* Wo = (const float*)d_in[10];
    const float* bo = (const float*)d_in[11];
    const float* to_ = (const float*)d_in[12];

    float* ws    = (float*)d_ws;
    float4* xz   = (float4*)ws;       // R float4s  (4*R floats)
    float* hscan = ws + 4 * R;        // R floats
    float* cfin  = ws + 5 * R;        // Bsz floats

    xz_kernel<<<2048, 256, 0, stream>>>(x, Wf, bf, tf, Wi, bi, ti, Wu, bu, tu, Wo, bo, to_, xz);
    scan_kernel<<<16, 64, 0, stream>>>((const float*)xz, Wf, Wi, Wu, Wo, hscan, cfin);

    const int total_f4 = (R + 2 * Bsz) * 32;              // 4,210,688
    bcast_kernel<<<total_f4 / 256, 256, 0, stream>>>(hscan, cfin, (float4*)d_out);
}

// Round 5
// 97.478 us; speedup vs baseline: 2.0767x; 2.0767x over previous
//
#include <hip/hip_runtime.h>
#include <hip/hip_bf16.h>

// QLSTM: T=512, B=256, D_IN=128, D_H=128.
// Gates are per-batch SCALARS broadcast over hidden dim => h,c uniform across
// hidden dim. comb@W[0] = x@W[0][:128] + h*sum(W[0][128:]).
// Pipeline: (1) xz GEMV -> packed float4 (pre-scaled by 1/2pi)  (mem-bound),
//           (2) 512-step scan: 64 blocks x 4 batch, block slice staged in
//               32 KB LDS, 4 lanes/batch DPP gate exchange, depth-2 ping-pong
//               register prefetch from LDS (named scalars, no arrays),
//           (3) broadcast h[t,b] to 128 cols + hx/cx tails (write-bound).

constexpr int T = 512;
constexpr int Bsz = 256;
constexpr int R = T * Bsz;          // 131072 rows
constexpr float INV2PI = 0.15915494309189535f;

// ---------------- Kernel 1: xz[row] = float4(zf,zi,zu,zo)/(2pi), row = t*B+b
__global__ __launch_bounds__(256) void xz_kernel(
    const float* __restrict__ x,
    const float* __restrict__ Wf, const float* __restrict__ bf, const float* __restrict__ tf,
    const float* __restrict__ Wi, const float* __restrict__ bi, const float* __restrict__ ti,
    const float* __restrict__ Wu, const float* __restrict__ bu, const float* __restrict__ tu,
    const float* __restrict__ Wo, const float* __restrict__ bo, const float* __restrict__ to_,
    float4* __restrict__ xz)
{
    const int wglobal = blockIdx.x * 4 + (threadIdx.x >> 6);   // 0..8191
    const int lane = threadIdx.x & 63;
    const int hl = lane & 31;            // lane within half-wave
    const int half = lane >> 5;          // which row of the pair

    const float4 wfv = ((const float4*)Wf)[hl];
    const float4 wiv = ((const float4*)Wi)[hl];
    const float4 wuv = ((const float4*)Wu)[hl];
    const float4 wov = ((const float4*)Wo)[hl];

    const float cf = bf[0] + tf[0];
    const float ci = bi[0] + ti[0];
    const float cu = bu[0] + tu[0];
    const float co = bo[0] + to_[0];

    for (int it = 0; it < 8; ++it) {
        const int row = (it * 8192 + wglobal) * 2 + half;
        const float4 xv = *(const float4*)(x + (size_t)row * 128 + hl * 4);

        float pf = xv.x * wfv.x + xv.y * wfv.y + xv.z * wfv.z + xv.w * wfv.w;
        float pi = xv.x * wiv.x + xv.y * wiv.y + xv.z * wiv.z + xv.w * wiv.w;
        float pu = xv.x * wuv.x + xv.y * wuv.y + xv.z * wuv.z + xv.w * wuv.w;
        float po = xv.x * wov.x + xv.y * wov.y + xv.z * wov.z + xv.w * wov.w;

#pragma unroll
        for (int off = 16; off; off >>= 1) {
            pf += __shfl_xor(pf, off, 64);
            pi += __shfl_xor(pi, off, 64);
            pu += __shfl_xor(pu, off, 64);
            po += __shfl_xor(po, off, 64);
        }
        if (hl == 0) {
            xz[row] = make_float4((pf + cf) * INV2PI, (pi + ci) * INV2PI,
                                  (pu + cu) * INV2PI, (po + co) * INV2PI);
        }
    }
}

// ---------------- Kernel 2: sequential scan, LDS-staged.
// tanh(c), |c|<=~2.1: Pade[5/4] c(945+105c^2+c^4)/(945+420c^2+15c^4), err ~2e-5.
__device__ __forceinline__ float tanh_p54(float c) {
    const float c2 = c * c;
    const float c4 = c2 * c2;
    const float num = fmaf(c2, 105.0f, 945.0f) + c4;
    const float den = fmaf(c4, 15.0f, fmaf(c2, 420.0f, 945.0f));
    return c * num * __builtin_amdgcn_rcpf(den);
}

template<int CTRL>
__device__ __forceinline__ float dppq(float x) {
    return __builtin_bit_cast(float,
        __builtin_amdgcn_mov_dpp(__builtin_bit_cast(int, x), CTRL, 0xF, 0xF, true));
}

constexpr int BPB = 4;                   // batch elements per scan block
constexpr int SCAN_BLOCKS = Bsz / BPB;   // 64

__global__ __launch_bounds__(256) void scan_kernel(
    const float4* __restrict__ xz,
    const float* __restrict__ Wf, const float* __restrict__ Wi,
    const float* __restrict__ Wu, const float* __restrict__ Wo,
    float* __restrict__ hscan, float* __restrict__ cfin)
{
    __shared__ float4 lds4[T * BPB];     // 32 KB: [t][bg] float4
    const int tid = threadIdx.x;
    const int bb = blockIdx.x * BPB;

    // ---- stage the block's xz slice into LDS (8 clustered float4 loads/thread)
#pragma unroll
    for (int r = 0; r < 8; ++r) {
        const int j = r * 256 + tid;                  // float4 index in slice
        lds4[j] = xz[(j >> 2) * Bsz + bb + (j & 3)];
    }

    // ---- per-gate hidden-weight sums (all 64 lanes of wave 0 participate)
    const int l = tid & 63;
    const int q = l & 3;                 // gate: 0=f 1=i 2=g 3=o
    const int part = l >> 2;             // 16 parts x 8 floats
    const float* Wsel = (q == 0) ? Wf : (q == 1) ? Wi : (q == 2) ? Wu : Wo;
    const float4 wa = *(const float4*)(Wsel + 128 + part * 8);
    const float4 wb = *(const float4*)(Wsel + 128 + part * 8 + 4);
    float s = (wa.x + wa.y) + (wa.z + wa.w) + ((wb.x + wb.y) + (wb.z + wb.w));
    s += __shfl_xor(s, 4, 64);
    s += __shfl_xor(s, 8, 64);
    s += __shfl_xor(s, 16, 64);
    s += __shfl_xor(s, 32, 64);
    const float sw = s * INV2PI;

    __syncthreads();
    if (tid >= BPB * 4) return;          // keep lanes 0..15 of wave 0

    const int batch = bb + (l >> 2);

    // unified odd deg-7 gate polynomial in v = cos(u):
    //   tanh lane (q==2): tanh(v); sigmoid lanes: 0.5 + 0.5*tanh(v/2) (folded).
    const bool tq = (q == 2);
    const float K0 = tq ? 0.0f        : 0.5f;
    const float K1 = tq ? 0.999904f   : 0.249976f;
    const float K3 = tq ? -0.331066f  : -0.0206916f;
    const float K5 = tq ? 0.120476f   : 0.00188244f;
    const float K7 = tq ? -0.0277200f : -0.000108281f;

    const float* zf = (const float*)lds4;   // float index: t*16 + l
    float h = 0.0f, c = 0.0f;
    float za = zf[0 * 16 + l];
    float zb = zf[1 * 16 + l];

#define QSTEP(ZZ, TCUR)                                            \
    {                                                              \
        const float u  = fmaf(h, sw, (ZZ));                        \
        const float v  = __builtin_amdgcn_cosf(u);                 \
        const float v2 = v * v;                                    \
        const float v4 = v2 * v2;                                  \
        const float phi = fmaf(v2, K7, K5);                        \
        const float plo = fmaf(v2, K3, K1);                        \
        const float p   = fmaf(v4, phi, plo);                      \
        const float gown = fmaf(v, p, K0);                         \
        const float f = dppq<0x00>(gown);                          \
        const float i = dppq<0x55>(gown);                          \
        const float g = dppq<0xAA>(gown);                          \
        const float o = dppq<0xFF>(gown);                          \
        c = fmaf(f, c, i * g);                                     \
        h = o * tanh_p54(c);                                       \
        if (q == 0) hscan[(TCUR) * Bsz + batch] = h;               \
    }

    for (int t = 0; t < T; t += 2) {
        const float zn0 = zf[(t + 2 < T ? t + 2 : T - 1) * 16 + l];
        QSTEP(za, t);
        za = zn0;
        const float zn1 = zf[(t + 3 < T ? t + 3 : T - 1) * 16 + l];
        QSTEP(zb, t + 1);
        zb = zn1;
    }
#undef QSTEP

    if (q == 0) cfin[batch] = c;
}

// ---------------- Kernel 3: broadcast h[t,b] across 128 hidden cols, + hx/cx tails.
__global__ __launch_bounds__(256) void bcast_kernel(
    const float* __restrict__ hscan, const float* __restrict__ cfin,
    float4* __restrict__ out)
{
    const unsigned i = blockIdx.x * 256u + threadIdx.x;  // float4 index
    const unsigned row = i >> 5;                          // output row (128 floats)
    float v;
    if (row < (unsigned)R) {
        v = hscan[row];
    } else {
        const unsigned r2 = row - (unsigned)R;
        v = (r2 < (unsigned)Bsz) ? hscan[(T - 1) * Bsz + r2] : cfin[r2 - (unsigned)Bsz];
    }
    out[i] = make_float4(v, v, v, v);
}

extern "C" void kernel_launch(void* const* d_in, const int* in_sizes, int n_in,
                              void* d_out, int out_size, void* d_ws, size_t ws_size,
                              hipStream_t stream)
{
    const float* x  = (const float*)d_in[0];
    const float* Wf = (const float*)d_in[1];
    const float* bf = (const float*)d_in[2];
    const float* tf = (const float*)d_in[3];
    const float* Wi = (const float*)d_in[4];
    const float* bi = (const float*)d_in[5];
    const float* ti = (const float*)d_in[6];
    const float* Wu = (const float*)d_in[7];
    const float* bu = (const float*)d_in[8];
    const float* tu = (const float*)d_in[9];
    const float* Wo = (const float*)d_in[10];
    const float* bo = (const float*)d_in[11];
    const float* to_ = (const float*)d_in[12];

    float* ws    = (float*)d_ws;
    float4* xz   = (float4*)ws;       // R float4s  (4*R floats)
    float* hscan = ws + 4 * R;        // R floats
    float* cfin  = ws + 5 * R;        // Bsz floats

    xz_kernel<<<2048, 256, 0, stream>>>(x, Wf, bf, tf, Wi, bi, ti, Wu, bu, tu, Wo, bo, to_, xz);
    scan_kernel<<<SCAN_BLOCKS, 256, 0, stream>>>(xz, Wf, Wi, Wu, Wo, hscan, cfin);

    const int total_f4 = (R + 2 * Bsz) * 32;              // 4,210,688
    bcast_kernel<<<total_f4 / 256, 256, 0, stream>>>(hscan, cfin, (float4*)d_out);
}

// Round 6
// 96.100 us; speedup vs baseline: 2.1064x; 1.0143x over previous
//
#include <hip/hip_runtime.h>
#include <hip/hip_bf16.h>

// QLSTM: T=512, B=256, D_IN=128, D_H=128.
// Gates are per-batch SCALARS broadcast over hidden dim => h,c uniform across
// hidden dim. comb@W[0] = x@W[0][:128] + h*sum(W[0][128:]).
// Pipeline: (1) xz GEMV -> packed float4 (pre-scaled by 1/2pi)  (mem-bound),
//           (2) 512-step scan: 4 blocks x 64 threads, ONE LANE = ONE BATCH
//               (all 4 gates in-lane: no DPP, no exec masks), carried
//               (c, tanh(c), o*sw_g) state, depth-8 prefetch in NAMED float4s,
//           (3) broadcast h[t,b] to 128 cols + hx/cx tails (write-bound).

constexpr int T = 512;
constexpr int Bsz = 256;
constexpr int R = T * Bsz;          // 131072 rows
constexpr float INV2PI = 0.15915494309189535f;

// ---------------- Kernel 1: xz[row] = float4(zf,zi,zu,zo)/(2pi), row = t*B+b
__global__ __launch_bounds__(256) void xz_kernel(
    const float* __restrict__ x,
    const float* __restrict__ Wf, const float* __restrict__ bf, const float* __restrict__ tf,
    const float* __restrict__ Wi, const float* __restrict__ bi, const float* __restrict__ ti,
    const float* __restrict__ Wu, const float* __restrict__ bu, const float* __restrict__ tu,
    const float* __restrict__ Wo, const float* __restrict__ bo, const float* __restrict__ to_,
    float4* __restrict__ xz)
{
    const int wglobal = blockIdx.x * 4 + (threadIdx.x >> 6);   // 0..8191
    const int lane = threadIdx.x & 63;
    const int hl = lane & 31;            // lane within half-wave
    const int half = lane >> 5;          // which row of the pair

    const float4 wfv = ((const float4*)Wf)[hl];
    const float4 wiv = ((const float4*)Wi)[hl];
    const float4 wuv = ((const float4*)Wu)[hl];
    const float4 wov = ((const float4*)Wo)[hl];

    const float cf = bf[0] + tf[0];
    const float ci = bi[0] + ti[0];
    const float cu = bu[0] + tu[0];
    const float co = bo[0] + to_[0];

    for (int it = 0; it < 8; ++it) {
        const int row = (it * 8192 + wglobal) * 2 + half;
        const float4 xv = *(const float4*)(x + (size_t)row * 128 + hl * 4);

        float pf = xv.x * wfv.x + xv.y * wfv.y + xv.z * wfv.z + xv.w * wfv.w;
        float pi = xv.x * wiv.x + xv.y * wiv.y + xv.z * wiv.z + xv.w * wiv.w;
        float pu = xv.x * wuv.x + xv.y * wuv.y + xv.z * wuv.z + xv.w * wuv.w;
        float po = xv.x * wov.x + xv.y * wov.y + xv.z * wov.z + xv.w * wov.w;

#pragma unroll
        for (int off = 16; off; off >>= 1) {
            pf += __shfl_xor(pf, off, 64);
            pi += __shfl_xor(pi, off, 64);
            pu += __shfl_xor(pu, off, 64);
            po += __shfl_xor(po, off, 64);
        }
        if (hl == 0) {
            xz[row] = make_float4((pf + cf) * INV2PI, (pi + ci) * INV2PI,
                                  (pu + cu) * INV2PI, (po + co) * INV2PI);
        }
    }
}

// ---------------- Kernel 2: sequential scan, one lane per batch element.
// tanh(c), |c|<=~2.1: Pade[5/4] c(945+105c^2+c^4)/(945+420c^2+15c^4), err ~2e-5.
__device__ __forceinline__ float tanh_p54(float c) {
    const float c2 = c * c;
    const float c4 = c2 * c2;
    const float num = fmaf(c2, 105.0f, 945.0f) + c4;
    const float den = fmaf(c4, 15.0f, fmaf(c2, 420.0f, 945.0f));
    return c * num * __builtin_amdgcn_rcpf(den);
}
// sigmoid(cos-arg v), |v|<=1: 0.5 + 0.5*tanh(v/2), odd deg-7 folded (err ~1e-5).
__device__ __forceinline__ float sigp(float v) {
    const float v2 = v * v;
    float p = fmaf(v2, -0.000108281f, 0.00188244f);
    p = fmaf(v2, p, -0.0206916f);
    p = fmaf(v2, p, 0.249976f);
    return fmaf(v, p, 0.5f);
}
// tanh(v), |v|<=1: odd deg-7 (err ~3e-4).
__device__ __forceinline__ float tanp(float v) {
    const float v2 = v * v;
    float p = fmaf(v2, -0.0277200f, 0.120476f);
    p = fmaf(v2, p, -0.331066f);
    p = fmaf(v2, p, 0.999904f);
    return v * p;
}

__device__ __forceinline__ float wsum(const float* __restrict__ W, int lane) {
    float s = W[128 + lane] + W[192 + lane];
#pragma unroll
    for (int off = 32; off; off >>= 1) s += __shfl_xor(s, off, 64);
    return s;  // butterfly: all lanes hold the sum
}

__global__ __launch_bounds__(64, 1) void scan_kernel(
    const float4* __restrict__ xz,
    const float* __restrict__ Wf, const float* __restrict__ Wi,
    const float* __restrict__ Wu, const float* __restrict__ Wo,
    float* __restrict__ hscan, float* __restrict__ cfin)
{
    const int lane = threadIdx.x;
    const int batch = blockIdx.x * 64 + lane;

    const float swf = wsum(Wf, lane) * INV2PI;
    const float swi = wsum(Wi, lane) * INV2PI;
    const float swu = wsum(Wu, lane) * INV2PI;
    const float swo = wsum(Wo, lane) * INV2PI;

    const float4* xzp = xz + batch;        // stride Bsz float4s per t
    float* hp = hscan + batch;

    // depth-8 prefetch in NAMED registers (no arrays -> nothing to spill)
    float4 z0 = xzp[0 * Bsz], z1 = xzp[1 * Bsz], z2 = xzp[2 * Bsz], z3 = xzp[3 * Bsz];
    float4 z4 = xzp[4 * Bsz], z5 = xzp[5 * Bsz], z6 = xzp[6 * Bsz], z7 = xzp[7 * Bsz];

    // carried state: c, tc = tanh(c), os_g = o * sw_g   (h = o*tc only for store)
    float c = 0.0f, tc = 0.0f;
    float osf = 0.0f, osi = 0.0f, osu = 0.0f, oso = 0.0f;

#define QSTEP(Z)                                                  \
    {                                                             \
        const float uf = fmaf(tc, osf, (Z).x);                    \
        const float ui = fmaf(tc, osi, (Z).y);                    \
        const float uu = fmaf(tc, osu, (Z).z);                    \
        const float uo = fmaf(tc, oso, (Z).w);                    \
        const float vf = __builtin_amdgcn_cosf(uf);               \
        const float vi = __builtin_amdgcn_cosf(ui);               \
        const float vu = __builtin_amdgcn_cosf(uu);               \
        const float vo = __builtin_amdgcn_cosf(uo);               \
        const float f  = sigp(vf);                                \
        const float i  = sigp(vi);                                \
        const float o  = sigp(vo);                                \
        const float g  = tanp(vu);                                \
        c  = fmaf(f, c, i * g);                                   \
        tc = tanh_p54(c);                                         \
        osf = o * swf; osi = o * swi;                             \
        osu = o * swu; oso = o * swo;                             \
        *hp = o * tc;                                             \
        hp += Bsz;                                                \
    }

    for (int tb = 0; tb < T - 8; tb += 8) {
        const float4* pr = xzp + (size_t)(tb + 8) * Bsz;
        QSTEP(z0); z0 = pr[0 * Bsz];
        QSTEP(z1); z1 = pr[1 * Bsz];
        QSTEP(z2); z2 = pr[2 * Bsz];
        QSTEP(z3); z3 = pr[3 * Bsz];
        QSTEP(z4); z4 = pr[4 * Bsz];
        QSTEP(z5); z5 = pr[5 * Bsz];
        QSTEP(z6); z6 = pr[6 * Bsz];
        QSTEP(z7); z7 = pr[7 * Bsz];
    }
    // epilogue: last 8 steps, no refill
    QSTEP(z0); QSTEP(z1); QSTEP(z2); QSTEP(z3);
    QSTEP(z4); QSTEP(z5); QSTEP(z6); QSTEP(z7);
#undef QSTEP

    cfin[batch] = c;
}

// ---------------- Kernel 3: broadcast h[t,b] across 128 hidden cols, + hx/cx tails.
__global__ __launch_bounds__(256) void bcast_kernel(
    const float* __restrict__ hscan, const float* __restrict__ cfin,
    float4* __restrict__ out)
{
    const unsigned i = blockIdx.x * 256u + threadIdx.x;  // float4 index
    const unsigned row = i >> 5;                          // output row (128 floats)
    float v;
    if (row < (unsigned)R) {
        v = hscan[row];
    } else {
        const unsigned r2 = row - (unsigned)R;
        v = (r2 < (unsigned)Bsz) ? hscan[(T - 1) * Bsz + r2] : cfin[r2 - (unsigned)Bsz];
    }
    out[i] = make_float4(v, v, v, v);
}

extern "C" void kernel_launch(void* const* d_in, const int* in_sizes, int n_in,
                              void* d_out, int out_size, void* d_ws, size_t ws_size,
                              hipStream_t stream)
{
    const float* x  = (const float*)d_in[0];
    const float* Wf = (const float*)d_in[1];
    const float* bf = (const float*)d_in[2];
    const float* tf = (const float*)d_in[3];
    const float* Wi = (const float*)d_in[4];
    const float* bi = (const float*)d_in[5];
    const float* ti = (const float*)d_in[6];
    const float* Wu = (const float*)d_in[7];
    const float* bu = (const float*)d_in[8];
    const float* tu = (const float*)d_in[9];
    const float* Wo = (const float*)d_in[10];
    const float* bo = (const float*)d_in[11];
    const float* to_ = (const float*)d_in[12];

    float* ws    = (float*)d_ws;
    float4* xz   = (float4*)ws;       // R float4s  (4*R floats)
    float* hscan = ws + 4 * R;        // R floats
    float* cfin  = ws + 5 * R;        // Bsz floats

    xz_kernel<<<2048, 256, 0, stream>>>(x, Wf, bf, tf, Wi, bi, ti, Wu, bu, tu, Wo, bo, to_, xz);
    scan_kernel<<<4, 64, 0, stream>>>(xz, Wf, Wi, Wu, Wo, hscan, cfin);

    const int total_f4 = (R + 2 * Bsz) * 32;              // 4,210,688
    bcast_kernel<<<total_f4 / 256, 256, 0, stream>>>(hscan, cfin, (float4*)d_out);
}